// Round 1
// baseline (84.891 us; speedup 1.0000x reference)
//
#include <hip/hip_runtime.h>
#include <math.h>

#define D    1024
#define BI   48
#define BC   48
#define RR   36
#define TT   40
#define EPSF 1e-5f
#define NRG  20   // row groups for BN partial sums (1920/20 = 96 rows each)

// ---------------- K0a: BN partial sums over cap_embed (Bc*T rows, D channels)
__global__ __launch_bounds__(256) void k_bnpart(const float* __restrict__ cap,
                                                float* __restrict__ ps,
                                                float* __restrict__ pss) {
    int bx = blockIdx.x;              // 80 blocks: 4 d-chunks x 20 row groups
    int dc = bx & 3, rg = bx >> 2;
    int d  = dc * 256 + threadIdx.x;
    int r0 = rg * (BC * TT / NRG);
    float s = 0.f, ss = 0.f;
    for (int r = r0; r < r0 + BC * TT / NRG; ++r) {
        float v = cap[(size_t)r * D + d];
        s += v; ss += v * v;
    }
    ps[rg * D + d]  = s;
    pss[rg * D + d] = ss;
}

// ---------------- K0b: finalize mean / scale
__global__ __launch_bounds__(256) void k_bnfin(const float* __restrict__ ps,
                                               const float* __restrict__ pss,
                                               float* __restrict__ mean,
                                               float* __restrict__ scale) {
    int d = blockIdx.x * 256 + threadIdx.x;
    float s = 0.f, ss = 0.f;
    for (int p = 0; p < NRG; ++p) { s += ps[p * D + d]; ss += pss[p * D + d]; }
    float m   = s * (1.f / (BC * TT));
    float var = ss * (1.f / (BC * TT)) - m * m;
    mean[d]  = m;
    scale[d] = 1.f / sqrtf(var + EPSF);
}

// ---------------- K1: img_q = mean over regions; img_n = l2norm(img_q)
__global__ __launch_bounds__(256) void k_imgq(const float* __restrict__ img,
                                              float* __restrict__ img_q,
                                              float* __restrict__ img_n) {
    int i = blockIdx.x, tid = threadIdx.x;
    float q[4];
    float ssq = 0.f;
#pragma unroll
    for (int j = 0; j < 4; ++j) {
        int d = j * 256 + tid;
        float s = 0.f;
        for (int r = 0; r < RR; ++r) s += img[((size_t)i * RR + r) * D + d];
        q[j] = s * (1.f / RR);
        img_q[(size_t)i * D + d] = q[j];
        ssq += q[j] * q[j];
    }
    for (int off = 32; off; off >>= 1) ssq += __shfl_xor(ssq, off, 64);
    __shared__ float sw[4];
    int wave = tid >> 6, lane = tid & 63;
    if (lane == 0) sw[wave] = ssq;
    __syncthreads();
    float rinv = 1.f / sqrtf(sw[0] + sw[1] + sw[2] + sw[3]);
#pragma unroll
    for (int j = 0; j < 4; ++j) {
        int d = j * 256 + tid;
        img_n[(size_t)i * D + d] = q[j] * rinv;
    }
}

// ---------------- K2: normalize + transpose cap -> capn[b][d][t]
__global__ __launch_bounds__(256) void k_norm(const float* __restrict__ cap,
                                              const float* __restrict__ mean,
                                              const float* __restrict__ scale,
                                              float* __restrict__ capn) {
    __shared__ float tile[256 * 41];   // pad 40 -> 41 to avoid bank conflicts
    int bx = blockIdx.x;               // 192 blocks: 48 b x 4 d-chunks
    int b = bx >> 2, dc = bx & 3;
    int tid = threadIdx.x;
    int d = dc * 256 + tid;
    float m = mean[d], sc = scale[d];
    for (int t = 0; t < TT; ++t)
        tile[tid * 41 + t] = (cap[((size_t)b * TT + t) * D + d] - m) * sc;
    __syncthreads();
    size_t base = ((size_t)b * D + dc * 256) * TT;
    for (int e = tid; e < 256 * TT; e += 256) {
        int dd = e / TT, t = e - dd * TT;
        capn[base + e] = tile[dd * 41 + t];
    }
}

// ---------------- K3: FiLM GEMMs: gammas/betas = img_q @ W^T + b
// wave-per-output-row: lane = k-slice, 48 i-accumulators, img_q chunk in LDS
__global__ __launch_bounds__(256) void k_film(const float* __restrict__ img_q,
                                              const float* __restrict__ Wg,
                                              const float* __restrict__ bg,
                                              const float* __restrict__ Wb,
                                              const float* __restrict__ bb,
                                              float* __restrict__ g1,
                                              float* __restrict__ be) {
    __shared__ float lq[48 * 256];
    int tid = threadIdx.x;
    int wave = tid >> 6, lane = tid & 63;
    int gw  = blockIdx.x * 4 + wave;   // 0..2047
    int mat = gw >> 10;                // 0: gamma, 1: beta
    int d   = gw & 1023;
    const float* W = mat ? Wb : Wg;
    float acc[48];
#pragma unroll
    for (int i = 0; i < 48; ++i) acc[i] = 0.f;
    for (int kc = 0; kc < 4; ++kc) {
        __syncthreads();
        for (int idx = tid; idx < 48 * 256; idx += 256) {
            int i = idx >> 8, k = idx & 255;
            lq[idx] = img_q[(size_t)i * D + kc * 256 + k];
        }
        __syncthreads();
        for (int k4 = 0; k4 < 4; ++k4) {
            float wv = W[(size_t)d * D + kc * 256 + k4 * 64 + lane];
#pragma unroll
            for (int i = 0; i < 48; ++i)
                acc[i] += wv * lq[i * 256 + k4 * 64 + lane];
        }
    }
#pragma unroll
    for (int i = 0; i < 48; ++i) {
        float v = acc[i];
        for (int off = 32; off; off >>= 1) v += __shfl_xor(v, off, 64);
        acc[i] = v;
    }
    if (lane == 0) {
        float* outp = mat ? be : g1;
        float badd = (mat ? bb[d] : bg[d]) + (mat ? 0.f : 1.f); // store 1+gamma
#pragma unroll
        for (int i = 0; i < 48; ++i) outp[(size_t)i * D + d] = acc[i] + badd;
    }
}

// ---------------- K4: fused Fovea + l2norm + cosine sim
__global__ __launch_bounds__(256) void k_fovea(const float* __restrict__ capn,
                                               const float* __restrict__ g1,
                                               const float* __restrict__ be,
                                               const float* __restrict__ img_n,
                                               float* __restrict__ out) {
    int blk = blockIdx.x;          // b-major: consecutive blocks share capn[b]
    int b = blk / BI, i = blk - b * BI;
    int tid = threadIdx.x;
    float dot = 0.f, ssum = 0.f;
#pragma unroll 1
    for (int j = 0; j < 4; ++j) {
        int d = j * 256 + tid;
        float g  = g1[(size_t)i * D + d];
        float bt = be[(size_t)i * D + d];
        const float* c = capn + ((size_t)b * D + d) * TT;
        float x[TT];
        float m = -INFINITY;
#pragma unroll
        for (int t = 0; t < TT; t += 4) {
            float4 cv = *(const float4*)(c + t);
            x[t + 0] = fmaf(cv.x, g, bt);
            x[t + 1] = fmaf(cv.y, g, bt);
            x[t + 2] = fmaf(cv.z, g, bt);
            x[t + 3] = fmaf(cv.w, g, bt);
            m = fmaxf(m, fmaxf(fmaxf(x[t], x[t + 1]), fmaxf(x[t + 2], x[t + 3])));
        }
        float s = 0.f, vmax = -INFINITY;
#pragma unroll
        for (int t = 0; t < TT; ++t) {
            float e = __expf(x[t] - m);
            s += e;
            vmax = fmaxf(vmax, e * x[t]);
        }
        float v = vmax / s;    // == max_t(softmax_t * x_t), since s > 0
        ssum += v * v;
        dot  += v * img_n[(size_t)i * D + d];
    }
    for (int off = 32; off; off >>= 1) {
        dot  += __shfl_xor(dot, off, 64);
        ssum += __shfl_xor(ssum, off, 64);
    }
    __shared__ float sd[4], sq[4];
    int wave = tid >> 6, lane = tid & 63;
    if (lane == 0) { sd[wave] = dot; sq[wave] = ssum; }
    __syncthreads();
    if (tid == 0) {
        float td = sd[0] + sd[1] + sd[2] + sd[3];
        float ts = sq[0] + sq[1] + sq[2] + sq[3];
        out[(size_t)i * BC + b] = td / sqrtf(ts);
    }
}

extern "C" void kernel_launch(void* const* d_in, const int* in_sizes, int n_in,
                              void* d_out, int out_size, void* d_ws, size_t ws_size,
                              hipStream_t stream) {
    const float* img = (const float*)d_in[0];
    const float* cap = (const float*)d_in[1];
    // d_in[2] = lens (unused)
    const float* Wg  = (const float*)d_in[3];
    const float* bg  = (const float*)d_in[4];
    const float* Wb  = (const float*)d_in[5];
    const float* bb  = (const float*)d_in[6];
    float* out = (float*)d_out;

    float* ws    = (float*)d_ws;
    float* ps    = ws;                     // 20*1024
    float* pss   = ps    + NRG * D;        // 20*1024
    float* mean  = pss   + NRG * D;        // 1024
    float* scale = mean  + D;              // 1024
    float* img_q = scale + D;              // 48*1024
    float* img_n = img_q + BI * D;         // 48*1024
    float* g1    = img_n + BI * D;         // 48*1024
    float* be    = g1    + BI * D;         // 48*1024
    float* capn  = be    + BI * D;         // 48*1024*40

    hipLaunchKernelGGL(k_bnpart, dim3(4 * NRG), dim3(256), 0, stream, cap, ps, pss);
    hipLaunchKernelGGL(k_imgq,   dim3(BI),      dim3(256), 0, stream, img, img_q, img_n);
    hipLaunchKernelGGL(k_bnfin,  dim3(4),       dim3(256), 0, stream, ps, pss, mean, scale);
    hipLaunchKernelGGL(k_norm,   dim3(192),     dim3(256), 0, stream, cap, mean, scale, capn);
    hipLaunchKernelGGL(k_film,   dim3(512),     dim3(256), 0, stream, img_q, Wg, bg, Wb, bb, g1, be);
    hipLaunchKernelGGL(k_fovea,  dim3(BI * BC), dim3(256), 0, stream, capn, g1, be, img_n, out);
}